// Round 5
// baseline (277.948 us; speedup 1.0000x reference)
//
#include <hip/hip_runtime.h>
#include <cmath>

typedef __bf16 bf16x8 __attribute__((ext_vector_type(8)));
typedef float  f32x4  __attribute__((ext_vector_type(4)));

template <int N> struct IC { static constexpr int v = N; };

// Shared geometry: BM=256 (=M), BK=64, 512 threads.
// MODE 0 (gates):  BN=64 = 4 gates x 16 cells, W window 64 rows x 256 K, S=4 substeps/window
// MODE 1 (vocab):  BN=128, W window 128 rows x 128 K, S=2
#define ATILE 32768        // A tile: 256 rows * 128B (bf16, swizzled)
#define LDS_W_OFF 65536    // W window buffers after 2 A buffers
#define WTILE_B 32768      // one W window as bf16 (64*512B or 128*256B)
// LDS: 2*32KB (A) + 2*32KB (W) = 128KB -> 1 block/CU

#define GLOAD_LDS16(g, l)                                                    \
    __builtin_amdgcn_global_load_lds(                                        \
        (const __attribute__((address_space(1))) unsigned int*)(g),          \
        (__attribute__((address_space(3))) unsigned int*)(l), 16, 0, 0)

__device__ __forceinline__ int swz(int row, int b) {          // 128B-row tiles (A)
    return row * 128 + (b ^ ((row & 7) << 4));
}
__device__ __forceinline__ bf16x8 cvt8(f32x4 a, f32x4 b) {
    bf16x8 r;
    r[0] = (__bf16)a[0]; r[1] = (__bf16)a[1]; r[2] = (__bf16)a[2]; r[3] = (__bf16)a[3];
    r[4] = (__bf16)b[0]; r[5] = (__bf16)b[1]; r[6] = (__bf16)b[2]; r[7] = (__bf16)b[3];
    return r;
}
template <int N> __device__ __forceinline__ void waitvm() {
    if constexpr (N == 0)  asm volatile("s_waitcnt vmcnt(0)" ::: "memory");
    else if constexpr (N == 4)  asm volatile("s_waitcnt vmcnt(4)" ::: "memory");
    else if constexpr (N == 12) asm volatile("s_waitcnt vmcnt(12)" ::: "memory");
}
__device__ __forceinline__ void waitlgkm() { asm volatile("s_waitcnt lgkmcnt(0)" ::: "memory"); }
#define SBAR()  __builtin_amdgcn_s_barrier()
#define SCHED() __builtin_amdgcn_sched_barrier(0)

__global__ __launch_bounds__(256)
void prep_xc(const float* __restrict__ cat, const float* __restrict__ x,
             const float* __restrict__ hid, unsigned char* __restrict__ A0)
{
    int id  = blockIdx.x * 256 + threadIdx.x;
    int row = id >> 9, col = (id & 511) * 8;
    const float* src = (col < 512)  ? cat + (size_t)row * 512 + col
                     : (col < 2048) ? x   + (size_t)row * 1536 + (col - 512)
                                    : hid + (size_t)row * 2048 + (col - 2048);
    f32x4 a = *(const f32x4*)src, b = *(const f32x4*)(src + 4);
    int ks = col >> 6, c8 = (col & 63) >> 3;
    *(bf16x8*)(A0 + (size_t)ks * ATILE + swz(row, c8 * 16)) = cvt8(a, b);
}

// MODE 0: gates GEMM + fused LSTM epilogue. out0=cnew, out1=hnew, A1out=bf16 hidden tiles.
// MODE 1: vocab GEMM. out0=logits (ld 32000), bias=B0.
template <int MODE>
__global__ __launch_bounds__(512, 2)
void gemm_fused(const unsigned char* __restrict__ At,
                const float* __restrict__ W0, const float* __restrict__ W1,
                const float* __restrict__ W2, const float* __restrict__ W3,
                const float* __restrict__ B0, const float* __restrict__ B1,
                const float* __restrict__ B2, const float* __restrict__ B3,
                const float* __restrict__ cell,
                float* __restrict__ out0, float* __restrict__ out1,
                unsigned char* __restrict__ A1out)
{
    __shared__ __align__(16) unsigned char lds[131072];

    constexpr int S       = (MODE == 0) ? 4 : 2;     // substeps per W window
    constexpr int NW      = (MODE == 0) ? 16 : 32;   // windows
    constexpr int NKT     = 64;                      // BK=64 substeps
    constexpr int WIN_K   = (MODE == 0) ? 256 : 128; // floats per row per window
    constexpr int ROWB    = (MODE == 0) ? 512 : 256; // bf16 window row bytes
    constexpr int ACC_M   = (MODE == 0) ? 2 : 4;
    constexpr int TSTEADY = (MODE == 0) ? 56 : 60;

    const int tid  = threadIdx.x;
    const int lane = tid & 63;
    const int wid  = tid >> 6;
    const int l15  = lane & 15;
    const int l4   = lane >> 4;
    const int wrM  = (MODE == 0) ? wid : (wid >> 1);   // wave M-row group
    const int wcN  = (MODE == 0) ? 0   : (wid & 1);    // wave N-col group

    int c0 = 0, wn0 = 0;
    int wrow_s, wchunk;
    const float* wsrc;
    if (MODE == 0) {
        c0 = blockIdx.x * 16;                 // 16 cell-cols, x4 gates = BN 64
        wrow_s = tid >> 3; wchunk = tid & 7;  // 64 rows x 8 chunks of 32 floats
        int gate = wrow_s >> 4;
        const float* Wg = (gate == 0) ? W0 : (gate == 1) ? W1 : (gate == 2) ? W2 : W3;
        wsrc = Wg + (size_t)(c0 + (wrow_s & 15)) * 4096 + wchunk * 32;
    } else {
        wn0 = blockIdx.x * 128;
        wrow_s = tid >> 2; wchunk = tid & 3;  // 128 rows x 4 chunks of 32 floats
        wsrc = W0 + (size_t)(wn0 + wrow_s) * 4096 + wchunk * 32;
    }
    const int sxs = (wrow_s & 7) << 4;

    f32x4 wreg[2][8];                  // W window regs, constexpr slot only
    f32x4 acc[ACC_M][4] = {};

    auto issueA = [&](int ks, int buf) {
        const unsigned char* src = At + (size_t)ks * ATILE + wid * 4096 + lane * 16;
        unsigned char* dst = lds + buf * ATILE + wid * 4096;
        #pragma unroll
        for (int i = 0; i < 4; ++i)
            GLOAD_LDS16(src + i * 1024, dst + i * 1024);
    };
    auto loadWwin = [&](int w, auto sl) {
        constexpr int SL = decltype(sl)::v;
        const float* p = wsrc + (size_t)w * WIN_K;
        #pragma unroll
        for (int i = 0; i < 8; ++i) wreg[SL][i] = *(const f32x4*)(p + i * 4);
    };
    auto storeWwin = [&](auto sl, int buf) {
        constexpr int SL = decltype(sl)::v;
        unsigned char* b = lds + LDS_W_OFF + buf * WTILE_B + wrow_s * ROWB;
        const int cb = wchunk * 64;
        *(bf16x8*)(b + ((cb +  0) ^ sxs)) = cvt8(wreg[SL][0], wreg[SL][1]);
        *(bf16x8*)(b + ((cb + 16) ^ sxs)) = cvt8(wreg[SL][2], wreg[SL][3]);
        *(bf16x8*)(b + ((cb + 32) ^ sxs)) = cvt8(wreg[SL][4], wreg[SL][5]);
        *(bf16x8*)(b + ((cb + 48) ^ sxs)) = cvt8(wreg[SL][6], wreg[SL][7]);
    };

    // ---- prologue: window 0 staged; A(0),A(1) + W(1) in flight ----
    loadWwin(0, IC<0>{});
    waitvm<0>(); SCHED();
    storeWwin(IC<0>{}, 0);
    issueA(0, 0); issueA(1, 1);
    loadWwin(1, IC<1>{});
    waitvm<12>(); SCHED();                 // drains A(0); leaves A(1)+W(1)
    waitlgkm();
    SBAR(); SCHED();

    auto step = [&](auto tsc, auto tailc, int t0) {
        constexpr int TS   = decltype(tsc)::v;
        constexpr int TAIL = decltype(tailc)::v;
        constexpr int SUB  = TS % S;
        constexpr int ABUF = TS & 1;
        constexpr int WB   = (TS / S) & 1;          // current window buffer/slot phase
        const int t = t0 + TS;
        const int w = t / S;
        unsigned char* abase = lds + ABUF * ATILE;
        unsigned char* wlds  = lds + LDS_W_OFF + WB * WTILE_B;

        // phase1: frag reads (tile t, window w, sub-k SUB)
        bf16x8 af[2][ACC_M], bw[2][4];
        #pragma unroll
        for (int kk = 0; kk < 2; ++kk) {
            #pragma unroll
            for (int m = 0; m < ACC_M; ++m) {
                int row = wrM * (ACC_M * 16) + m * 16 + l15;
                af[kk][m] = *(const bf16x8*)(abase + swz(row, kk * 64 + l4 * 16));
            }
            #pragma unroll
            for (int n = 0; n < 4; ++n) {
                int row = wcN * 64 + n * 16 + l15;
                bw[kk][n] = *(const bf16x8*)(wlds + row * ROWB +
                              ((SUB * 128 + kk * 64 + l4 * 16) ^ ((row & 7) << 4)));
            }
        }
        waitlgkm(); SCHED();
        SBAR(); SCHED();                       // A-buf ABUF now reusable

        // phase2: issue A(t+2), (window-start) issue W(w+2), MFMA(t), (window-end) stage W(w+1)
        if (t + 2 < NKT) issueA(t + 2, ABUF);
        if constexpr (SUB == 0) { if (w + 2 < NW) loadWwin(w + 2, IC<WB>{}); }
        #pragma unroll
        for (int kk = 0; kk < 2; ++kk)
            #pragma unroll
            for (int m = 0; m < ACC_M; ++m)
                #pragma unroll
                for (int n = 0; n < 4; ++n)
                    acc[m][n] = __builtin_amdgcn_mfma_f32_16x16x32_bf16(
                        af[kk][m], bw[kk][n], acc[m][n], 0, 0, 0);
        if constexpr (SUB == S - 1) {
            if (w + 1 < NW) storeWwin(IC<WB ^ 1>{}, WB ^ 1);   // regs drained by earlier waits
        }
        // end-of-step wait: land A(t+1) (FIFO-counted; see schedule derivation)
        constexpr int VM = TAIL ? ((MODE == 0) ? (TS < 6 ? 4 : 0) : (TS < 2 ? 4 : 0))
                                : ((MODE == 0) ? ((TS & 3) < 2 ? 12 : 4) : 12);
        waitvm<VM>(); SCHED();
        if constexpr (SUB == S - 1) waitlgkm();
        SBAR(); SCHED();
    };

    auto blk = [&](auto self, auto tsc, auto tailc, int t0) -> void {
        constexpr int TS = decltype(tsc)::v;
        step(tsc, tailc, t0);
        if constexpr (TS + 1 < 2 * S) self(self, IC<TS + 1>{}, tailc, t0);
    };
    int t0 = 0;
    for (; t0 < TSTEADY; t0 += 2 * S) blk(blk, IC<0>{}, IC<0>{}, t0);
    blk(blk, IC<0>{}, IC<1>{}, t0);          // tail block (2S steps, conservative waits)

    if constexpr (MODE == 0) {
        // fused LSTM epilogue: acc[m][0..3] = f,i,g,o for rows wid*32+m*16+l4*4+j, cell c0+l15
        float* lh = (float*)lds;             // 256 x 16 fp32 staging for A1 transpose
        const int ccol = c0 + l15;
        const float bfv = B0[ccol], biv = B1[ccol], bcv = B2[ccol], bov = B3[ccol];
        #pragma unroll
        for (int m = 0; m < 2; ++m) {
            #pragma unroll
            for (int j = 0; j < 4; ++j) {
                int row = wid * 32 + m * 16 + l4 * 4 + j;
                float f = 1.0f / (1.0f + __expf(-(acc[m][0][j] + bfv)));
                float i = 1.0f / (1.0f + __expf(-(acc[m][1][j] + biv)));
                float g = tanhf(acc[m][2][j] + bcv);
                float o = 1.0f / (1.0f + __expf(-(acc[m][3][j] + bov)));
                float cn = f * cell[(size_t)row * 4096 + ccol] + i * g;
                float hn = o * tanhf(cn);
                out0[(size_t)row * 4096 + ccol] = cn;
                out1[(size_t)row * 4096 + ccol] = hn;
                lh[row * 16 + l15] = hn;
            }
        }
        __syncthreads();
        {   // build A1 bf16x8 vectors: 512 threads = 256 rows x 2 halves
            int row = tid >> 1, half = tid & 1;
            const float* p = lh + row * 16 + half * 8;
            f32x4 a = *(const f32x4*)p, b = *(const f32x4*)(p + 4);
            int c8 = ((c0 & 63) >> 3) + half;
            *(bf16x8*)(A1out + (size_t)(c0 >> 6) * ATILE + swz(row, c8 * 16)) = cvt8(a, b);
        }
    } else {
        // vocab epilogue: bias + store. C/D map col=lane&15, row=(lane>>4)*4+j
        #pragma unroll
        for (int n = 0; n < 4; ++n) {
            int col = wcN * 64 + n * 16 + l15;
            float bias = B0 ? 0.0f : 0.0f;   // placeholder; real bias below
            bias = B1[wn0 + col];            // B1 carries bout
            #pragma unroll
            for (int m = 0; m < 4; ++m) {
                int row = wrM * 64 + m * 16 + l4 * 4;
                f32x4 v = acc[m][n];
                #pragma unroll
                for (int j = 0; j < 4; ++j)
                    out0[(size_t)(row + j) * 32000 + wn0 + col] = v[j] + bias;
            }
        }
    }
}

__global__ __launch_bounds__(256)
void logsoftmax_inplace(float* __restrict__ out)
{
    float* row    = out + (size_t)blockIdx.x * 32000;
    const int tid = threadIdx.x;
    __shared__ float redm[4], reds[4];

    float m = -1e30f, s = 0.0f;
    for (int i = tid; i < 8000; i += 256) {
        f32x4 v = *(const f32x4*)(row + i * 4);
        float t = fmaxf(fmaxf(v[0], v[1]), fmaxf(v[2], v[3]));
        float nm = fmaxf(m, t);
        s = s * __expf(m - nm) + __expf(v[0] - nm) + __expf(v[1] - nm)
                               + __expf(v[2] - nm) + __expf(v[3] - nm);
        m = nm;
    }
    #pragma unroll
    for (int off = 32; off; off >>= 1) {
        float om = __shfl_xor(m, off), os = __shfl_xor(s, off);
        float nm = fmaxf(m, om);
        s = s * __expf(m - nm) + os * __expf(om - nm);
        m = nm;
    }
    if ((tid & 63) == 0) { redm[tid >> 6] = m; reds[tid >> 6] = s; }
    __syncthreads();
    {
        float M = fmaxf(fmaxf(redm[0], redm[1]), fmaxf(redm[2], redm[3]));
        float S = reds[0] * __expf(redm[0] - M) + reds[1] * __expf(redm[1] - M)
                + reds[2] * __expf(redm[2] - M) + reds[3] * __expf(redm[3] - M);
        m = M; s = S;
    }
    float lse = m + logf(s);

    for (int i = tid; i < 8000; i += 256) {
        f32x4 v = *(const f32x4*)(row + i * 4);
        v[0] -= lse; v[1] -= lse; v[2] -= lse; v[3] -= lse;
        *(f32x4*)(row + i * 4) = v;
    }
}

extern "C" void kernel_launch(void* const* d_in, const int* in_sizes, int n_in,
                              void* d_out, int out_size, void* d_ws, size_t ws_size,
                              hipStream_t stream)
{
    const float* cat  = (const float*)d_in[0];
    const float* x    = (const float*)d_in[1];
    const float* hid  = (const float*)d_in[2];
    const float* cell = (const float*)d_in[3];
    const float* Wf   = (const float*)d_in[4];
    const float* bf   = (const float*)d_in[5];
    const float* Wi   = (const float*)d_in[6];
    const float* bi   = (const float*)d_in[7];
    const float* Wc   = (const float*)d_in[8];
    const float* bc   = (const float*)d_in[9];
    const float* Wo   = (const float*)d_in[10];
    const float* bo   = (const float*)d_in[11];
    const float* Wout = (const float*)d_in[12];
    const float* bout = (const float*)d_in[13];
    float* out = (float*)d_out;

    // ws: A0 bf16-tiled xc (2MB) | A1 bf16-tiled hidden_new (2MB)
    unsigned char* A0 = (unsigned char*)d_ws;
    unsigned char* A1 = A0 + (size_t)64 * ATILE;

    // d_out: [logits 256x32000 | cell_new 256x4096 | hidden_new 256x4096]
    float* cnew = out + 8192000;
    float* hnew = out + 9240576;

    prep_xc<<<512, 256, 0, stream>>>(cat, x, hid, A0);
    // gates GEMM + fused LSTM: 256 blocks own 16 cell-cols x 4 gates each
    gemm_fused<0><<<256, 512, 0, stream>>>(A0, Wf, Wi, Wc, Wo, bf, bi, bc, bo,
                                           cell, cnew, hnew, A1);
    // vocab GEMM: 250 blocks x 128 cols  (B1 carries bout)
    gemm_fused<1><<<250, 512, 0, stream>>>(A1, Wout, nullptr, nullptr, nullptr,
                                           nullptr, bout, nullptr, nullptr,
                                           nullptr, out, nullptr, nullptr);
    logsoftmax_inplace<<<256, 256, 0, stream>>>(out);
}